// Round 7
// baseline (3322.153 us; speedup 1.0000x reference)
//
#include <hip/hip_runtime.h>
#include <math.h>

// SRNN: T=128, B=256, D=512, H=1024, O=20
// v_new = ALPHA*v + z@Wrec_eff^T + x_t@Win^T - z*THR ; z_new = v_new > THR
// vo_new = KAPPA*vo + z_new@Wout^T ; out = softmax(vo, axis=2)
//
// ORDER CONTRACT (validated R6/R7 — DO NOT BREAK):
//   P (K=1024): ((c[0,320)+c[320,640))+c[640,960))+c[960,1024)
//   Q (K=512) :   c[0,320)+c[320,512)
//   per-chunk: single sequential ascending-k fma chain per element
//   elementwise: ((ALPHA_f32*v + P) + Q) - z   (all _rn, left-assoc)
//   diag as z*0 in-chain (WrecT diag pre-zeroed)
// R15 (this round):
//   * R14 lesson: wave=1b x 64h forces b32 gathers (256 B/instr); LDS is
//     instr-rate-bound -> R14 sat at its own throughput floor (16 us).
//   * New step geometry: wave = 1 b x 128 h (b64, same-row, conflict-free)
//     x 4 waves/block (256 thr) -> grid 512 (64 bg x 8 ht), 16 stages x
//     64 rows, 2 x 32 KB dbuf + 4 KB u8 klist = 68 KB -> 2 blocks/CU.
//     All three requirements met: b64 width + 2 blocks/CU + conflict-free.
//   * Chunk boundaries 320/640/960 = words 10/20/30 are STAGE-aligned
//     (stage = 2 words): acc0=st0-4, acc1=st5-9, acc2=st10-14, acc3=st15.
//     No split lists. klist build is wave-private (lanes 0-31 expand own
//     wave's b; in-order LDS -> no barrier). u8 entries ((word&1)<<5|bit),
//     masked &0x3F at use so even garbage reads stay in-buffer.

#define T_ 128
#define B_ 256
#define D_ 512
#define H_ 1024
#define O_ 20
#define ST_ 127
#define WPB 32
#define ALPHA_F ((float)0.95122942450071400909)
#define KAPPA_F ((float)0.95122942450071400909)

typedef float v2f __attribute__((ext_vector_type(2)));

#if defined(__has_builtin)
#if __has_builtin(__builtin_elementwise_fma)
#define PK_FMA(a, b, c) __builtin_elementwise_fma(a, b, c)
#endif
#if __has_builtin(__builtin_amdgcn_global_load_lds)
#define HAVE_GLL 1
#endif
#endif
#ifndef PK_FMA
static __device__ inline v2f pk_fma_impl(v2f a, v2f b, v2f c) {
    v2f r; r[0] = __fmaf_rn(a[0], b[0], c[0]); r[1] = __fmaf_rn(a[1], b[1], c[1]);
    return r;
}
#define PK_FMA(a, b, c) pk_fma_impl(a, b, c)
#endif

static __device__ __forceinline__ void f2acc(float2& a, const float2 b) {
    a.x = __fadd_rn(a.x, b.x);
    a.y = __fadd_rn(a.y, b.y);
}

static __device__ __forceinline__ unsigned spread16(unsigned x) {
    x &= 0xFFFFu;
    x = (x | (x << 8)) & 0x00FF00FFu;
    x = (x | (x << 4)) & 0x0F0F0F0Fu;
    x = (x | (x << 2)) & 0x33333333u;
    x = (x | (x << 1)) & 0x55555555u;
    return x;
}

// ------------------------------------------------------------ transpose ----
__global__ __launch_bounds__(256) void transpose_k(
    const float* __restrict__ src, float* __restrict__ dst,
    int rows, int cols, int zero_diag)
{
    __shared__ float tile[32][33];
    const int c0 = blockIdx.x * 32;
    const int r0 = blockIdx.y * 32;
    const int tid = threadIdx.x;
    const int lr = tid >> 3;
    const int lc = (tid & 7) * 4;
    const float4 vv = *(const float4*)(src + (size_t)(r0 + lr) * cols + c0 + lc);
    tile[lr][lc+0] = vv.x; tile[lr][lc+1] = vv.y;
    tile[lr][lc+2] = vv.z; tile[lr][lc+3] = vv.w;
    __syncthreads();
    const int wc = lr;
    const int wr = lc;
    float4 o;
    o.x = tile[wr+0][wc]; o.y = tile[wr+1][wc];
    o.z = tile[wr+2][wc]; o.w = tile[wr+3][wc];
    if (zero_diag) {
        const int c = c0 + wc;
        if (c == r0 + wr + 0) o.x = 0.f;
        if (c == r0 + wr + 1) o.y = 0.f;
        if (c == r0 + wr + 2) o.z = 0.f;
        if (c == r0 + wr + 3) o.w = 0.f;
    }
    *(float4*)(dst + (size_t)(c0 + wc) * rows + r0 + wr) = o;
}

// ---------------------------------------------------------------- init ----
__global__ __launch_bounds__(256) void srnn_init(
    float* __restrict__ v, unsigned* __restrict__ z0)
{
    const int i = blockIdx.x * 256 + threadIdx.x;
    if (i < B_ * H_)  v[i]  = 0.0f;
    if (i < B_ * WPB) z0[i] = 0u;
}

// ------------------------------------------- Q precompute (group GEMM) ----
#define SWC(r) ((((r) >> 3) & 3) << 2)
__global__ __launch_bounds__(256) void srnn_qsum(
    const float* __restrict__ x,      // [T,B,D]
    const float* __restrict__ WinT,   // [512][1024]
    float* __restrict__ qs,           // [nsl][B][H]
    int s0, int nsl)
{
    __shared__ float wt[32][68];
    __shared__ float xt[32][68];
    const int nwg = nsl * 64;
    const int rb  = (int)blockIdx.x;
    const int lb  = (rb & 7) * (nwg >> 3) + (rb >> 3);
    const int sl = lb >> 6;
    const int t = lb & 63;
    const int h0 = (t & 15) << 6;
    const int b0 = (t >> 4) << 6;
    const int tid = threadIdx.x;
    const int tx4 = (tid & 15) << 2;
    const int ty4 = (tid >> 4) << 2;
    const float* xs = x + (size_t)(s0 + sl) * (B_ * D_);

    const int idxa = tid * 2, idxb = tid * 2 + 1;
    const int wra = idxa >> 4, wca = (idxa & 15) << 2;
    const int wrb = idxb >> 4, wcb = (idxb & 15) << 2;
    const int bra = idxa >> 3, kqa = (idxa & 7) << 2;
    const int brb = idxb >> 3, kqb = (idxb & 7) << 2;

    v2f accA[4][2], accB[4][2];
    #pragma unroll
    for (int i = 0; i < 4; ++i) {
        accA[i][0]=(v2f)0.f; accA[i][1]=(v2f)0.f;
        accB[i][0]=(v2f)0.f; accB[i][1]=(v2f)0.f;
    }

    float4 wp0, wp1, xp0, xp1;
    auto qload = [&](int kc) {
        wp0 = *(const float4*)(WinT + (size_t)(kc*32 + wra)*H_ + h0 + wca);
        wp1 = *(const float4*)(WinT + (size_t)(kc*32 + wrb)*H_ + h0 + wcb);
        xp0 = *(const float4*)(xs + (size_t)(b0+bra)*D_ + kc*32 + kqa);
        xp1 = *(const float4*)(xs + (size_t)(b0+brb)*D_ + kc*32 + kqb);
    };
    auto qstore = [&]() {
        *(float4*)&wt[wra][wca] = wp0;
        *(float4*)&wt[wrb][wcb] = wp1;
        xt[kqa+0][bra ^ SWC(kqa+0)]=xp0.x; xt[kqa+1][bra ^ SWC(kqa+1)]=xp0.y;
        xt[kqa+2][bra ^ SWC(kqa+2)]=xp0.z; xt[kqa+3][bra ^ SWC(kqa+3)]=xp0.w;
        xt[kqb+0][brb ^ SWC(kqb+0)]=xp1.x; xt[kqb+1][brb ^ SWC(kqb+1)]=xp1.y;
        xt[kqb+2][brb ^ SWC(kqb+2)]=xp1.z; xt[kqb+3][brb ^ SWC(kqb+3)]=xp1.w;
    };
    auto qinner = [&](v2f (&ACC)[4][2]) {
        #pragma unroll
        for (int kk = 0; kk < 32; ++kk) {        // k ascending — contract
            const float4 zf = *(const float4*)&xt[kk][ty4 ^ SWC(kk)];
            const float4 wf = *(const float4*)&wt[kk][tx4];
            v2f wlo, whi;
            wlo[0]=wf.x; wlo[1]=wf.y; whi[0]=wf.z; whi[1]=wf.w;
            const float zz[4] = {zf.x, zf.y, zf.z, zf.w};
            #pragma unroll
            for (int i = 0; i < 4; ++i) {
                v2f zv; zv[0]=zz[i]; zv[1]=zz[i];
                ACC[i][0] = PK_FMA(zv, wlo, ACC[i][0]);
                ACC[i][1] = PK_FMA(zv, whi, ACC[i][1]);
            }
        }
    };

    qload(0);
    for (int kc = 0; kc < 10; ++kc) {            // Q0: k 0..319
        __syncthreads();
        qstore();
        __syncthreads();
        qload(kc + 1);
        qinner(accA);
    }
    for (int kc = 10; kc < 16; ++kc) {           // Q1: k 320..511
        __syncthreads();
        qstore();
        __syncthreads();
        if (kc < 15) qload(kc + 1);
        qinner(accB);
    }

    float* qd = qs + (size_t)sl * (B_ * H_);
    #pragma unroll
    for (int i = 0; i < 4; ++i) {
        float4 o;
        o.x = __fadd_rn(accA[i][0][0], accB[i][0][0]);
        o.y = __fadd_rn(accA[i][0][1], accB[i][0][1]);
        o.z = __fadd_rn(accA[i][1][0], accB[i][1][0]);
        o.w = __fadd_rn(accA[i][1][1], accB[i][1][1]);
        *(float4*)(qd + (size_t)(b0 + ty4 + i) * H_ + h0 + tx4) = o;
    }
}

// -------------------------- fused sparse step: P + v-update + z-pack -----
// grid = 512 blocks (2/CU): ht = bid&7 (128 h, XCD-pinned WrecT slice),
// bg = bid>>3 (64 groups of 4 b). 256 threads = 4 waves; wave = 1 b x 128 h
// (float2/lane, conflict-free same-row b64 gathers). 16 stages x 64 rows;
// 2 x 32 KB LDS buffers, 1-deep prefetch, vmcnt(0)+ONE barrier per stage.
// Chunk mapping (stage-aligned): st0-4 acc0 | st5-9 acc1 | st10-14 acc2 |
// st15 acc3. klist u8 row-in-stage, wave-private build.
#define STG_FLOATS (64 * 128)   // 32 KB per buffer

static __device__ __forceinline__ void issue_stage(
    const float* __restrict__ WrecT, float* buf,
    int s, int ht, int w, int tid)
{
    const int ln = tid & 63;
#ifdef HAVE_GLL
    #pragma unroll
    for (int i = 0; i < 8; ++i) {
        const int c = i * 4 + w;                 // 32 chunks x 1 KB (2 rows)
        const int row = s * 64 + c * 2 + (ln >> 5);
        const float* gs = WrecT + (size_t)row * H_ + ht * 128 + ((ln & 31) << 2);
        float* ld = buf + c * 256;               // wave-uniform base
        __builtin_amdgcn_global_load_lds(
            (const __attribute__((address_space(1))) void*)gs,
            (__attribute__((address_space(3))) void*)ld, 16, 0, 0);
    }
#else
    #pragma unroll
    for (int i = 0; i < 8; ++i) {
        const int c = i * 4 + w;
        const int row = s * 64 + c * 2 + (ln >> 5);
        const float4 tv = *(const float4*)(WrecT + (size_t)row * H_ + ht * 128 + ((ln & 31) << 2));
        *(float4*)&buf[c * 256 + ln * 4] = tv;
    }
#endif
}

#ifdef HAVE_GLL
#define WAITV0() asm volatile("s_waitcnt vmcnt(0)" ::: "memory")
#define STEPBAR() __builtin_amdgcn_s_barrier()
#else
#define WAITV0()
#define STEPBAR() __syncthreads()
#endif

__global__ __launch_bounds__(256, 2) void srnn_step(
    const float* __restrict__ WrecT,    // [1024k][1024h], diag zeroed
    const float* __restrict__ qsum_s,   // [B,H] = fadd(Q0,Q1) for this step
    const unsigned* __restrict__ zin,   // [B,WPB]  z_s
    unsigned* __restrict__ zout,        // [B,WPB]  z_{s+1} (zhist slice)
    float* __restrict__ v)              // [B,H]
{
    __shared__ float wt[2][STG_FLOATS];          // 64 KB
    __shared__ unsigned char klist[16][4][64];   // 4 KB (row-in-stage ids)

    const int bid = (int)blockIdx.x;
    const int ht = bid & 7;                      // XCD-pinned 128-h slice
    const int bg = bid >> 3;                     // 0..63
    const int tid = threadIdx.x;
    const int w = tid >> 6;     // wave id == local b (0..3)
    const int ln = tid & 63;
    const int b = bg * 4 + w;

    // z load first (oldest in vmcnt order); lane ln (<32) holds word ln
    unsigned zword = 0u;
    if (ln < 32) zword = zin[(size_t)b * WPB + ln];

    issue_stage(WrecT, &wt[0][0], 0, ht, w, tid);

    // ---- spike lists (wave-private): lane ln<32 expands word ln;
    //      stage = ln>>1; entry = ((word&1)<<5)|bit, ascending — contract.
    const int myc = __popc(zword);               // lanes >=32: zword==0
    const int pmy = __shfl_up(myc, 1, 64);       // even partner's count
    const int pre = (ln & 1) ? pmy : 0;
    const int tot = pre + myc;                   // at odd ln: stage count
    if (ln < 32) {
        unsigned char* kd = &klist[ln >> 1][w][pre];
        const unsigned base = (unsigned)((ln & 1) << 5);
        int ofs = 0;
        unsigned tw = zword;
        while (tw) {
            const int j = __builtin_ctz(tw);
            tw &= tw - 1;
            kd[ofs++] = (unsigned char)(base + (unsigned)j);
        }
    }
    // klist[..][w] written and read by wave w only -> in-order LDS, no sync

    float2 acc0 = {0.f, 0.f}, acc1 = {0.f, 0.f};
    float2 acc2 = {0.f, 0.f}, acc3 = {0.f, 0.f};

    // Batched gather over stage SS's list. Ascending i_ — contract.
    // Offsets: row * 512 B (row stride = 128 floats); &0x3F mask keeps even
    // garbage (beyond n) in-buffer — but loop bounds make that unreachable.
    auto proc = [&](float2& ACC, const unsigned char* kl_, const char* wb_,
                    int n_) {
        int i_ = 0;
        for (; i_ + 8 <= n_; i_ += 8) {
            uint2 kk_ = *(const uint2*)(kl_ + i_);
            kk_.x &= 0x3F3F3F3Fu; kk_.y &= 0x3F3F3F3Fu;
            const float2 r0_ = *(const float2*)(wb_ + ((kk_.x & 0xFFu) << 9));
            const float2 r1_ = *(const float2*)(wb_ + (((kk_.x >> 8) & 0xFFu) << 9));
            const float2 r2_ = *(const float2*)(wb_ + (((kk_.x >> 16) & 0xFFu) << 9));
            const float2 r3_ = *(const float2*)(wb_ + ((kk_.x >> 24) << 9));
            const float2 r4_ = *(const float2*)(wb_ + ((kk_.y & 0xFFu) << 9));
            const float2 r5_ = *(const float2*)(wb_ + (((kk_.y >> 8) & 0xFFu) << 9));
            const float2 r6_ = *(const float2*)(wb_ + (((kk_.y >> 16) & 0xFFu) << 9));
            const float2 r7_ = *(const float2*)(wb_ + ((kk_.y >> 24) << 9));
            f2acc(ACC, r0_); f2acc(ACC, r1_); f2acc(ACC, r2_); f2acc(ACC, r3_);
            f2acc(ACC, r4_); f2acc(ACC, r5_); f2acc(ACC, r6_); f2acc(ACC, r7_);
        }
        if (i_ + 4 <= n_) {
            unsigned kk_ = *(const unsigned*)(kl_ + i_);
            kk_ &= 0x3F3F3F3Fu;
            const float2 r0_ = *(const float2*)(wb_ + ((kk_ & 0xFFu) << 9));
            const float2 r1_ = *(const float2*)(wb_ + (((kk_ >> 8) & 0xFFu) << 9));
            const float2 r2_ = *(const float2*)(wb_ + (((kk_ >> 16) & 0xFFu) << 9));
            const float2 r3_ = *(const float2*)(wb_ + ((kk_ >> 24) << 9));
            f2acc(ACC, r0_); f2acc(ACC, r1_); f2acc(ACC, r2_); f2acc(ACC, r3_);
            i_ += 4;
        }
        for (; i_ < n_; ++i_) {
            const unsigned j_ = (unsigned)(kl_[i_] & 0x3F);
            const float2 r_ = *(const float2*)(wb_ + (j_ << 9));
            f2acc(ACC, r_);
        }
    };

#define NN(SS) __builtin_amdgcn_readfirstlane(__shfl(tot, (SS) * 2 + 1, 64))
#define WB(SS) (((const char*)&wt[(SS) & 1][0]) + (ln << 3))
#define KL(SS) (&klist[SS][w][0])
// Per stage: wait own stage-s DMAs -> barrier (all waves done with the
// OTHER buffer) -> issue s+1 into the other buffer -> gather stage s.
#define STEP_S(SS, ACC) do { \
    WAITV0(); \
    STEPBAR(); \
    asm volatile("" ::: "memory"); \
    if ((SS) < 15) issue_stage(WrecT, &wt[((SS) + 1) & 1][0], (SS) + 1, ht, w, tid); \
    proc(ACC, KL(SS), WB(SS), NN(SS)); \
} while (0)

    STEP_S(0, acc0);  STEP_S(1, acc0);  STEP_S(2, acc0);  STEP_S(3, acc0);  STEP_S(4, acc0);
    STEP_S(5, acc1);  STEP_S(6, acc1);  STEP_S(7, acc1);  STEP_S(8, acc1);  STEP_S(9, acc1);
    STEP_S(10, acc2); STEP_S(11, acc2); STEP_S(12, acc2); STEP_S(13, acc2); STEP_S(14, acc2);
    STEP_S(15, acc3);
#undef NN
#undef WB
#undef KL
#undef STEP_S

    // ---- epilogue: P tree + exact elementwise chain + spike pack ----
    const int h0 = ht * 128 + ln * 2;
    const size_t bh = (size_t)b * H_ + h0;
    const float2 qv = *(const float2*)(qsum_s + bh);
    const float2 vv = *(const float2*)(v + bh);
    const unsigned zwrd = (unsigned)__shfl((int)zword, ht * 4 + (ln >> 4), 64);
    const int bb0 = (ln & 15) * 2;

    const float a0c[2] = {acc0.x, acc0.y};
    const float a1c[2] = {acc1.x, acc1.y};
    const float a2c[2] = {acc2.x, acc2.y};
    const float a3c[2] = {acc3.x, acc3.y};
    const float qc[2]  = {qv.x, qv.y};
    const float vc[2]  = {vv.x, vv.y};

    float vn2[2];
    #pragma unroll
    for (int m = 0; m < 2; ++m) {
        const float P  = __fadd_rn(__fadd_rn(__fadd_rn(a0c[m], a1c[m]), a2c[m]), a3c[m]);
        const float zs = ((zwrd >> (bb0 + m)) & 1u) ? 1.f : 0.f;
        const float t1 = __fmul_rn(ALPHA_F, vc[m]);
        const float t2 = __fadd_rn(t1, P);
        const float t3 = __fadd_rn(t2, qc[m]);
        vn2[m] = __fsub_rn(t3, zs);
    }
    float2 vst; vst.x = vn2[0]; vst.y = vn2[1];
    *(float2*)(v + bh) = vst;

    // spike pack: wave covers 128 h = words ht*4 .. ht*4+3 of its b.
    const unsigned long long bx = __ballot(vn2[0] > 1.0f);   // even h bits
    const unsigned long long by = __ballot(vn2[1] > 1.0f);   // odd h bits
    if (ln < 4) {
        const unsigned ex = (unsigned)((bx >> (ln * 16)) & 0xFFFFull);
        const unsigned ey = (unsigned)((by >> (ln * 16)) & 0xFFFFull);
        const unsigned word = spread16(ex) | (spread16(ey) << 1);
        zout[(size_t)b * WPB + ht * 4 + ln] = word;
    }
}

// --------------------------------------------- deferred readout: zo ------
__global__ __launch_bounds__(256) void srnn_zo(
    const unsigned* __restrict__ zhist, // [ST][B][WPB]
    const float* __restrict__ w_out,    // [O,H]
    float* __restrict__ zo)             // [ST][B][O]
{
    __shared__ float red[16][16][O_ + 1];   // 26.9 KB
    const int s  = blockIdx.x >> 4;
    const int bg = blockIdx.x & 15;
    const int tid = threadIdx.x;
    const int bl  = tid >> 4;           // 0..15 local b
    const int seg = tid & 15;           // h segment of 64
    const int b = bg * 16 + bl;
    const unsigned* zr = zhist + ((size_t)s * B_ + b) * WPB;
    const unsigned w0 = zr[seg * 2 + 0];
    const unsigned w1 = zr[seg * 2 + 1];

    float a[O_];
    #pragma unroll
    for (int o = 0; o < O_; ++o) a[o] = 0.f;
    const int hb = seg * 64;
    for (int j = 0; j < 32; ++j) {
        if ((w0 >> j) & 1u) {
            #pragma unroll
            for (int o = 0; o < O_; ++o) a[o] += w_out[(size_t)o * H_ + hb + j];
        }
    }
    for (int j = 0; j < 32; ++j) {
        if ((w1 >> j) & 1u) {
            #pragma unroll
            for (int o = 0; o < O_; ++o) a[o] += w_out[(size_t)o * H_ + hb + 32 + j];
        }
    }
    #pragma unroll
    for (int o = 0; o < O_; ++o) red[bl][seg][o] = a[o];
    __syncthreads();
    for (int ww = tid; ww < 16 * O_; ww += 256) {
        const int bl2 = ww / O_, o = ww % O_;
        float sum = 0.f;
        #pragma unroll
        for (int g = 0; g < 16; ++g) sum += red[bl2][g][o];
        zo[((size_t)s * B_ + bg * 16 + bl2) * O_ + o] = sum;
    }
}

// --------------------------------------- kappa-scan + softmax (fp32) -----
__global__ __launch_bounds__(64) void srnn_scan(
    const float* __restrict__ zo,   // [ST][B][O]
    float* __restrict__ out)        // [T][B][O]
{
    __shared__ float vos[T_][O_];   // 10 KB
    const int b = blockIdx.x;
    const int tid = threadIdx.x;
    if (tid < O_) {
        float vo = 0.f;
        vos[0][tid] = 0.f;          // vo[0] stays zero
        for (int sp = 0; sp < ST_; ++sp) {
            vo = KAPPA_F * vo + zo[((size_t)sp * B_ + b) * O_ + tid];
            vos[sp + 1][tid] = vo;
        }
    }
    __syncthreads();
    for (int t = tid; t < T_; t += 64) {
        float m = -1e30f;
        #pragma unroll
        for (int o = 0; o < O_; ++o) m = fmaxf(m, vos[t][o]);
        float e[O_];
        float ssum = 0.f;
        #pragma unroll
        for (int o = 0; o < O_; ++o) {
            const float ee = expf(vos[t][o] - m);
            e[o] = ee;
            ssum += ee;
        }
        const float inv = 1.f / ssum;
        #pragma unroll
        for (int o = 0; o < O_; ++o)
            out[((size_t)t * B_ + b) * O_ + o] = e[o] * inv;
    }
}

extern "C" void kernel_launch(void* const* d_in, const int* in_sizes, int n_in,
                              void* d_out, int out_size, void* d_ws, size_t ws_size,
                              hipStream_t stream) {
    const float* x     = (const float*)d_in[0];   // [128,256,512]
    const float* w_in  = (const float*)d_in[1];   // [1024,512]
    const float* w_rec = (const float*)d_in[2];   // [1024,1024]
    const float* w_out = (const float*)d_in[3];   // [20,1024]
    float* out = (float*)d_out;                   // [128,256,20]

    // ws layout: WrecT(4MB) | WinT(2MB) | v(1MB) | z0(32KB) | zhist(4.15MB)
    //            | zo(2.6MB) | qbuf(G MB, adaptive)
    float*    WrecT = (float*)d_ws;
    float*    WinT  = WrecT + (size_t)H_ * H_;
    float*    v     = WinT  + (size_t)D_ * H_;
    unsigned* z0    = (unsigned*)(v + (size_t)B_ * H_);
    unsigned* zhist = z0 + (size_t)B_ * WPB;
    float*    zo    = (float*)(zhist + (size_t)ST_ * B_ * WPB);
    float*    qbuf  = zo + (size_t)ST_ * B_ * O_;

    const size_t used = (size_t)((char*)qbuf - (char*)d_ws);
    const size_t qstep = (size_t)B_ * H_ * sizeof(float);   // 1 MB per step
    size_t avail = (ws_size > used) ? (ws_size - used) : 0;
    int G = (int)(avail / qstep);
    if (G < 1)  G = 1;
    if (G > ST_) G = ST_;

    transpose_k<<<dim3(32, 32), 256, 0, stream>>>(w_rec, WrecT, H_, H_, 1);
    transpose_k<<<dim3(16, 32), 256, 0, stream>>>(w_in,  WinT,  H_, D_, 0);
    srnn_init<<<(B_ * H_ + 255) / 256, 256, 0, stream>>>(v, z0);

    const unsigned* zprev = z0;
    for (int s0 = 0; s0 < ST_; s0 += G) {
        const int gc = (ST_ - s0 < G) ? (ST_ - s0) : G;
        srnn_qsum<<<gc * 64, 256, 0, stream>>>(x, WinT, qbuf, s0, gc);
        for (int sl = 0; sl < gc; ++sl) {
            const int s = s0 + sl;
            unsigned* zcur = zhist + (size_t)s * B_ * WPB;
            srnn_step<<<512, 256, 0, stream>>>(
                WrecT, qbuf + (size_t)sl * B_ * H_, zprev, zcur, v);
            zprev = zcur;
        }
    }

    srnn_zo<<<ST_ * 16, 256, 0, stream>>>(zhist, w_out, zo);
    srnn_scan<<<B_, 64, 0, stream>>>(zo, out);
}

// Round 8
// 2492.846 us; speedup vs baseline: 1.3327x; 1.3327x over previous
//
#include <hip/hip_runtime.h>
#include <math.h>

// SRNN: T=128, B=256, D=512, H=1024, O=20
// v_new = ALPHA*v + z@Wrec_eff^T + x_t@Win^T - z*THR ; z_new = v_new > THR
// vo_new = KAPPA*vo + z_new@Wout^T ; out = softmax(vo, axis=2)
//
// ORDER CONTRACT (validated R6/R7 — DO NOT BREAK):
//   P (K=1024): ((c[0,320)+c[320,640))+c[640,960))+c[960,1024)
//   Q (K=512) :   c[0,320)+c[320,512)
//   per-chunk: single sequential ascending-k fma chain per element
//   elementwise: ((ALPHA_f32*v + P) + Q) - z   (all _rn, left-assoc)
//   diag as z*0 in-chain (WrecT diag pre-zeroed)
// R16 (this round):
//   * step kernel: R14-verbatim (best measured; b-per-block=8 minimizes
//     staging = 256/bpb * 4MB/step; LDS-BW floor ~8us, measured 15.6).
//     R15's 4-b blocks doubled staging -> reverted. vmcnt-reorder is
//     UNSOUND (waves gather rows DMA'd by other waves; wait-own->barrier
//     must precede gather) -> schedule unchanged.
//   * qsum v2: LDS-BW-bound (34 GB reads @69TB/s = 493us ~= measured 450).
//     8x8 microtile @ 128x128 tile: 4 b128 reads / 64 MACs -> 17 GB ->
//     ~250us floor. Thread's 8 h/b = two float4 groups 64 apart (2-way
//     bank aliasing = free). Per-element chain unchanged (kk ascending,
//     kc 0-9 accA / 10-15 accB, final fadd) -> bit-identical.

#define T_ 128
#define B_ 256
#define D_ 512
#define H_ 1024
#define O_ 20
#define ST_ 127
#define WPB 32
#define ALPHA_F ((float)0.95122942450071400909)
#define KAPPA_F ((float)0.95122942450071400909)

typedef float v2f __attribute__((ext_vector_type(2)));

#if defined(__has_builtin)
#if __has_builtin(__builtin_elementwise_fma)
#define PK_FMA(a, b, c) __builtin_elementwise_fma(a, b, c)
#endif
#if __has_builtin(__builtin_amdgcn_global_load_lds)
#define HAVE_GLL 1
#endif
#endif
#ifndef PK_FMA
static __device__ inline v2f pk_fma_impl(v2f a, v2f b, v2f c) {
    v2f r; r[0] = __fmaf_rn(a[0], b[0], c[0]); r[1] = __fmaf_rn(a[1], b[1], c[1]);
    return r;
}
#define PK_FMA(a, b, c) pk_fma_impl(a, b, c)
#endif

// ------------------------------------------------------------ transpose ----
__global__ __launch_bounds__(256) void transpose_k(
    const float* __restrict__ src, float* __restrict__ dst,
    int rows, int cols, int zero_diag)
{
    __shared__ float tile[32][33];
    const int c0 = blockIdx.x * 32;
    const int r0 = blockIdx.y * 32;
    const int tid = threadIdx.x;
    const int lr = tid >> 3;
    const int lc = (tid & 7) * 4;
    const float4 vv = *(const float4*)(src + (size_t)(r0 + lr) * cols + c0 + lc);
    tile[lr][lc+0] = vv.x; tile[lr][lc+1] = vv.y;
    tile[lr][lc+2] = vv.z; tile[lr][lc+3] = vv.w;
    __syncthreads();
    const int wc = lr;
    const int wr = lc;
    float4 o;
    o.x = tile[wr+0][wc]; o.y = tile[wr+1][wc];
    o.z = tile[wr+2][wc]; o.w = tile[wr+3][wc];
    if (zero_diag) {
        const int c = c0 + wc;
        if (c == r0 + wr + 0) o.x = 0.f;
        if (c == r0 + wr + 1) o.y = 0.f;
        if (c == r0 + wr + 2) o.z = 0.f;
        if (c == r0 + wr + 3) o.w = 0.f;
    }
    *(float4*)(dst + (size_t)(c0 + wc) * rows + r0 + wr) = o;
}

// ---------------------------------------------------------------- init ----
__global__ __launch_bounds__(256) void srnn_init(
    float* __restrict__ v, unsigned* __restrict__ z0)
{
    const int i = blockIdx.x * 256 + threadIdx.x;
    if (i < B_ * H_)  v[i]  = 0.0f;
    if (i < B_ * WPB) z0[i] = 0u;
}

// ------------------------------------------- Q precompute (group GEMM) ----
// qs[sl][b][h] = fadd( chain(k=0..319), chain(k=320..511) ) of x[s0+sl]@WinT.
// 128x128 (b,h) tiles, 8x8 microtile (thread's 8 h = {tx*4..+3, 64+tx*4..+3},
// 8 b likewise), reg-prefetch double buffering. grid = nsl*16 blocks
// (divisible by 8 -> bijective XCD remap).
#define QPAD 132
__global__ __launch_bounds__(256) void srnn_qsum(
    const float* __restrict__ x,      // [T,B,D]
    const float* __restrict__ WinT,   // [512][1024]
    float* __restrict__ qs,           // [nsl][B][H]
    int s0, int nsl)
{
    __shared__ float wt[32][QPAD];    // [k][h] 16.9 KB
    __shared__ float xt[32][QPAD];    // [k][b] 16.9 KB
    const int nwg = nsl * 16;
    const int rb  = (int)blockIdx.x;
    const int lb  = (rb & 7) * (nwg >> 3) + (rb >> 3);
    const int sl = lb >> 4;
    const int t  = lb & 15;
    const int h0 = (t & 7) << 7;      // 8 h-tiles of 128
    const int b0 = (t >> 3) << 7;     // 2 b-tiles of 128
    const int tid = threadIdx.x;
    const int tx4 = (tid & 15) << 2;  // h sub-offset (and +64)
    const int ty4 = (tid >> 4) << 2;  // b sub-offset (and +64)
    const float* xs = x + (size_t)(s0 + sl) * (B_ * D_);

    v2f accA[8][4], accB[8][4];
    #pragma unroll
    for (int i = 0; i < 8; ++i)
        #pragma unroll
        for (int j = 0; j < 4; ++j) { accA[i][j] = (v2f)0.f; accB[i][j] = (v2f)0.f; }

    float4 wr_[4], xr_[4];
    auto qload = [&](int kc) {
        #pragma unroll
        for (int q = 0; q < 4; ++q) {
            const int fi = q * 256 + tid;
            wr_[q] = *(const float4*)(WinT +
                (size_t)(kc * 32 + (fi >> 5)) * H_ + h0 + ((fi & 31) << 2));
            xr_[q] = *(const float4*)(xs +
                (size_t)(b0 + (fi >> 3)) * D_ + kc * 32 + ((fi & 7) << 2));
        }
    };
    auto qstore = [&]() {
        #pragma unroll
        for (int q = 0; q < 4; ++q) {
            const int fi = q * 256 + tid;
            *(float4*)&wt[fi >> 5][(fi & 31) << 2] = wr_[q];
            const int br = fi >> 3, kq = (fi & 7) << 2;
            xt[kq + 0][br] = xr_[q].x; xt[kq + 1][br] = xr_[q].y;
            xt[kq + 2][br] = xr_[q].z; xt[kq + 3][br] = xr_[q].w;
        }
    };
    auto qinner = [&](v2f (&ACC)[8][4]) {
        #pragma unroll
        for (int kk = 0; kk < 32; ++kk) {        // k ascending — contract
            const float4 xf0 = *(const float4*)&xt[kk][ty4];
            const float4 xf1 = *(const float4*)&xt[kk][64 + ty4];
            const float4 wf0 = *(const float4*)&wt[kk][tx4];
            const float4 wf1 = *(const float4*)&wt[kk][64 + tx4];
            v2f w00, w01, w10, w11;
            w00[0] = wf0.x; w00[1] = wf0.y; w01[0] = wf0.z; w01[1] = wf0.w;
            w10[0] = wf1.x; w10[1] = wf1.y; w11[0] = wf1.z; w11[1] = wf1.w;
            const float zz[8] = {xf0.x, xf0.y, xf0.z, xf0.w,
                                 xf1.x, xf1.y, xf1.z, xf1.w};
            #pragma unroll
            for (int i = 0; i < 8; ++i) {
                v2f zv; zv[0] = zz[i]; zv[1] = zz[i];
                ACC[i][0] = PK_FMA(zv, w00, ACC[i][0]);
                ACC[i][1] = PK_FMA(zv, w01, ACC[i][1]);
                ACC[i][2] = PK_FMA(zv, w10, ACC[i][2]);
                ACC[i][3] = PK_FMA(zv, w11, ACC[i][3]);
            }
        }
    };

    qload(0);
    for (int kc = 0; kc < 10; ++kc) {            // Q0: k 0..319
        __syncthreads();
        qstore();
        __syncthreads();
        qload(kc + 1);
        qinner(accA);
    }
    for (int kc = 10; kc < 16; ++kc) {           // Q1: k 320..511
        __syncthreads();
        qstore();
        __syncthreads();
        if (kc < 15) qload(kc + 1);
        qinner(accB);
    }

    float* qd = qs + (size_t)sl * (B_ * H_);
    #pragma unroll
    for (int i = 0; i < 8; ++i) {
        const int brow = b0 + ((i < 4) ? (ty4 + i) : (64 + ty4 + (i - 4)));
        float4 o0, o1;
        o0.x = __fadd_rn(accA[i][0][0], accB[i][0][0]);
        o0.y = __fadd_rn(accA[i][0][1], accB[i][0][1]);
        o0.z = __fadd_rn(accA[i][1][0], accB[i][1][0]);
        o0.w = __fadd_rn(accA[i][1][1], accB[i][1][1]);
        o1.x = __fadd_rn(accA[i][2][0], accB[i][2][0]);
        o1.y = __fadd_rn(accA[i][2][1], accB[i][2][1]);
        o1.z = __fadd_rn(accA[i][3][0], accB[i][3][0]);
        o1.w = __fadd_rn(accA[i][3][1], accB[i][3][1]);
        *(float4*)(qd + (size_t)brow * H_ + h0 + tx4) = o0;
        *(float4*)(qd + (size_t)brow * H_ + h0 + 64 + tx4) = o1;
    }
}

// -------------------------- fused sparse step: P + v-update + z-pack -----
// R14-verbatim. grid = 512 blocks (2/CU): ht = (bid&7)*2+((bid>>3)&1)
// (64 h, XCD-pinned), bg = bid>>4 (8 b). 512 threads = 8 waves; wave =
// 1 b x 64 h (1 float/lane). 8 stages x 128 k-rows; 2 x 32 KB LDS buffers,
// 1-deep prefetch, vmcnt(0)+ONE barrier per stage. klist u16 byte offsets.
// Chunk mapping: st0,1,2a->acc0; 2b,3,4->acc1; 5,6,7a->acc2; 7b->acc3.
#define STG_FLOATS (128 * 64)   // 32 KB per buffer

static __device__ __forceinline__ void issue_stage8(
    const float* __restrict__ WrecT, float* buf,
    int s, int ht, int w, int tid)
{
#ifdef HAVE_GLL
    #pragma unroll
    for (int i = 0; i < 4; ++i) {
        const int row = s * 128 + i * 32 + (tid >> 4);
        const float* gs = WrecT + (size_t)row * H_ + ht * 64 + ((tid & 15) << 2);
        float* ld = buf + (i * 32 + 4 * w) * 64;       // wave-uniform base
        __builtin_amdgcn_global_load_lds(
            (const __attribute__((address_space(1))) void*)gs,
            (__attribute__((address_space(3))) void*)ld, 16, 0, 0);
    }
#else
    #pragma unroll
    for (int i = 0; i < 4; ++i) {
        const int row = s * 128 + i * 32 + (tid >> 4);
        const float4 tv = *(const float4*)(WrecT + (size_t)row * H_ + ht * 64 + ((tid & 15) << 2));
        *(float4*)&buf[(i * 32 + (tid >> 4)) * 64 + ((tid & 15) << 2)] = tv;
    }
#endif
}

#ifdef HAVE_GLL
#define WAITV0() asm volatile("s_waitcnt vmcnt(0)" ::: "memory")
#define STEPBAR() __builtin_amdgcn_s_barrier()
#else
#define WAITV0()
#define STEPBAR() __syncthreads()
#endif

__global__ __launch_bounds__(512, 4) void srnn_step(
    const float* __restrict__ WrecT,    // [1024k][1024h], diag zeroed
    const float* __restrict__ qsum_s,   // [B,H] = fadd(Q0,Q1) for this step
    const unsigned* __restrict__ zin,   // [B,WPB]  z_s
    unsigned* __restrict__ zout,        // [B,WPB]  z_{s+1} (zhist slice)
    float* __restrict__ v)              // [B,H]
{
    __shared__ float wt[2][STG_FLOATS];            // 64 KB
    __shared__ unsigned short klist[8][8][128];    // 16 KB (byte offsets)

    const int bid = (int)blockIdx.x;
    const int ht = ((bid & 7) << 1) | ((bid >> 3) & 1);   // 0..15
    const int bg = bid >> 4;                              // 0..31
    const int tid = threadIdx.x;
    const int w = tid >> 6;     // wave id == local b
    const int ln = tid & 63;
    const int b = bg * 8 + w;

    // z load first (oldest in vmcnt order) so list build only drains it
    unsigned zword = 0u;
    if (ln < 32) zword = zin[(size_t)b * WPB + ln];

    issue_stage8(WrecT, &wt[0][0], 0, ht, w, tid);

    // ---- spike lists: lane ln owns z-word ln; stage = ln>>2 --------------
    const int myc = __popc(zword);                 // unconditional (shfl src)
    const int gbase = ln & ~3;
    const int p0 = __shfl(myc, gbase | 0, 64);
    const int p1 = __shfl(myc, gbase | 1, 64);
    const int p2 = __shfl(myc, gbase | 2, 64);
    const int q = ln & 3;
    const int pre = (q > 0 ? p0 : 0) + (q > 1 ? p1 : 0) + (q > 2 ? p2 : 0);
    const int tot = pre + myc;                     // at q==3: stage count
    if (ln < 32) {
        unsigned short* kd = &klist[ln >> 2][w][pre];
        const unsigned base = (unsigned)(q << 13); // word q: 32 rows * 256 B
        int ofs = 0;
        unsigned tw = zword;
        while (tw) {                               // ascending bits — contract
            const int j = __builtin_ctz(tw);
            tw &= tw - 1;
            kd[ofs++] = (unsigned short)(base + ((unsigned)j << 8));
        }
    }
    // klist[..][w] is wave-private -> no block sync needed (in-order LDS)

    const int n0 = __builtin_amdgcn_readfirstlane(__shfl(tot, 3,  64));
    const int n1 = __builtin_amdgcn_readfirstlane(__shfl(tot, 7,  64));
    const int n2 = __builtin_amdgcn_readfirstlane(__shfl(tot, 11, 64));
    const int n3 = __builtin_amdgcn_readfirstlane(__shfl(tot, 15, 64));
    const int n4 = __builtin_amdgcn_readfirstlane(__shfl(tot, 19, 64));
    const int n5 = __builtin_amdgcn_readfirstlane(__shfl(tot, 23, 64));
    const int n6 = __builtin_amdgcn_readfirstlane(__shfl(tot, 27, 64));
    const int n7 = __builtin_amdgcn_readfirstlane(__shfl(tot, 31, 64));
    const int sp2 = __builtin_amdgcn_readfirstlane(__shfl(pre, 10, 64)); // k=320
    const int sp7 = __builtin_amdgcn_readfirstlane(__shfl(pre, 30, 64)); // k=960

    float acc0 = 0.f, acc1 = 0.f, acc2 = 0.f, acc3 = 0.f;

    // Batched gather over [lo,hi) of a stage list. Ascending i_ — contract.
    auto proc = [&](float& ACC, const unsigned short* kl_, const char* wb_,
                    int lo, int hi) {
        int i_ = lo;
        while (i_ < hi && (i_ & 7)) {              // align to 8 (split ranges)
            const float r_ = *(const float*)(wb_ + kl_[i_]);
            ACC = __fadd_rn(ACC, r_);
            ++i_;
        }
        for (; i_ + 8 <= hi; i_ += 8) {
            const uint4 kk_ = *(const uint4*)(kl_ + i_);
            const float r0_ = *(const float*)(wb_ + (kk_.x & 0xFFFFu));
            const float r1_ = *(const float*)(wb_ + (kk_.x >> 16));
            const float r2_ = *(const float*)(wb_ + (kk_.y & 0xFFFFu));
            const float r3_ = *(const float*)(wb_ + (kk_.y >> 16));
            const float r4_ = *(const float*)(wb_ + (kk_.z & 0xFFFFu));
            const float r5_ = *(const float*)(wb_ + (kk_.z >> 16));
            const float r6_ = *(const float*)(wb_ + (kk_.w & 0xFFFFu));
            const float r7_ = *(const float*)(wb_ + (kk_.w >> 16));
            ACC = __fadd_rn(ACC, r0_); ACC = __fadd_rn(ACC, r1_);
            ACC = __fadd_rn(ACC, r2_); ACC = __fadd_rn(ACC, r3_);
            ACC = __fadd_rn(ACC, r4_); ACC = __fadd_rn(ACC, r5_);
            ACC = __fadd_rn(ACC, r6_); ACC = __fadd_rn(ACC, r7_);
        }
        if (i_ + 4 <= hi) {
            const uint2 kk_ = *(const uint2*)(kl_ + i_);
            const float r0_ = *(const float*)(wb_ + (kk_.x & 0xFFFFu));
            const float r1_ = *(const float*)(wb_ + (kk_.x >> 16));
            const float r2_ = *(const float*)(wb_ + (kk_.y & 0xFFFFu));
            const float r3_ = *(const float*)(wb_ + (kk_.y >> 16));
            ACC = __fadd_rn(ACC, r0_); ACC = __fadd_rn(ACC, r1_);
            ACC = __fadd_rn(ACC, r2_); ACC = __fadd_rn(ACC, r3_);
            i_ += 4;
        }
        for (; i_ < hi; ++i_) {
            const float r_ = *(const float*)(wb_ + kl_[i_]);
            ACC = __fadd_rn(ACC, r_);
        }
    };

#define WB(SS) (((const char*)&wt[(SS) & 1][0]) + (ln << 2))
#define KL(SS) (&klist[SS][w][0])
// Per stage: wait own stage-s DMAs -> barrier (all waves done with the
// OTHER buffer AND all DMAs landed) -> issue s+1 -> gather stage s.
#define STEP_HEAD(SS) do { \
    WAITV0(); \
    STEPBAR(); \
    asm volatile("" ::: "memory"); \
    if ((SS) < 7) issue_stage8(WrecT, &wt[((SS) + 1) & 1][0], (SS) + 1, ht, w, tid); \
} while (0)

    STEP_HEAD(0); proc(acc0, KL(0), WB(0), 0, n0);
    STEP_HEAD(1); proc(acc0, KL(1), WB(1), 0, n1);
    STEP_HEAD(2); proc(acc0, KL(2), WB(2), 0, sp2);     // k 256..319
                  proc(acc1, KL(2), WB(2), sp2, n2);    // k 320..383
    STEP_HEAD(3); proc(acc1, KL(3), WB(3), 0, n3);
    STEP_HEAD(4); proc(acc1, KL(4), WB(4), 0, n4);
    STEP_HEAD(5); proc(acc2, KL(5), WB(5), 0, n5);
    STEP_HEAD(6); proc(acc2, KL(6), WB(6), 0, n6);
    STEP_HEAD(7); proc(acc2, KL(7), WB(7), 0, sp7);     // k 896..959
                  proc(acc3, KL(7), WB(7), sp7, n7);    // k 960..1023
#undef WB
#undef KL
#undef STEP_HEAD

    // ---- epilogue: P tree + exact elementwise chain + spike pack ----
    const int h0 = ht * 64 + ln;
    const size_t bh = (size_t)b * H_ + h0;
    const float qv = qsum_s[bh];
    const float vv = v[bh];
    const unsigned zwrd = (unsigned)__shfl((int)zword, ht * 2 + (ln >> 5), 64);
    const float zs = ((zwrd >> (ln & 31)) & 1u) ? 1.f : 0.f;

    const float P  = __fadd_rn(__fadd_rn(__fadd_rn(acc0, acc1), acc2), acc3);
    const float t1 = __fmul_rn(ALPHA_F, vv);
    const float t2 = __fadd_rn(t1, P);
    const float t3 = __fadd_rn(t2, qv);
    const float vn = __fsub_rn(t3, zs);
    v[bh] = vn;

    const unsigned long long bx = __ballot(vn > 1.0f);
    if (ln == 0)
        zout[(size_t)b * WPB + ht * 2 + 0] = (unsigned)(bx & 0xFFFFFFFFull);
    if (ln == 32)
        zout[(size_t)b * WPB + ht * 2 + 1] = (unsigned)(bx >> 32);
}

// --------------------------------------------- deferred readout: zo ------
__global__ __launch_bounds__(256) void srnn_zo(
    const unsigned* __restrict__ zhist, // [ST][B][WPB]
    const float* __restrict__ w_out,    // [O,H]
    float* __restrict__ zo)             // [ST][B][O]
{
    __shared__ float red[16][16][O_ + 1];   // 26.9 KB
    const int s  = blockIdx.x >> 4;
    const int bg = blockIdx.x & 15;
    const int tid = threadIdx.x;
    const int bl  = tid >> 4;           // 0..15 local b
    const int seg = tid & 15;           // h segment of 64
    const int b = bg * 16 + bl;
    const unsigned* zr = zhist + ((size_t)s * B_ + b) * WPB;
    const unsigned w0 = zr[seg * 2 + 0];
    const unsigned w1 = zr[seg * 2 + 1];

    float a[O_];
    #pragma unroll
    for (int o = 0; o < O_; ++o) a[o] = 0.f;
    const int hb = seg * 64;
    for (int j = 0; j < 32; ++j) {
        if ((w0 >> j) & 1u) {
            #pragma unroll
            for (int o = 0; o < O_; ++o) a[o] += w_out[(size_t)o * H_ + hb + j];
        }
    }
    for (int j = 0; j < 32; ++j) {
        if ((w1 >> j) & 1u) {
            #pragma unroll
            for (int o = 0; o < O_; ++o) a[o] += w_out[(size_t)o * H_ + hb + 32 + j];
        }
    }
    #pragma unroll
    for (int o = 0; o < O_; ++o) red[bl][seg][o] = a[o];
    __syncthreads();
    for (int ww = tid; ww < 16 * O_; ww += 256) {
        const int bl2 = ww / O_, o = ww % O_;
        float sum = 0.f;
        #pragma unroll
        for (int g = 0; g < 16; ++g) sum += red[bl2][g][o];
        zo[((size_t)s * B_ + bg * 16 + bl2) * O_ + o] = sum;
    }
}

// --------------------------------------- kappa-scan + softmax (fp32) -----
__global__ __launch_bounds__(64) void srnn_scan(
    const float* __restrict__ zo,   // [ST][B][O]
    float* __restrict__ out)        // [T][B][O]
{
    __shared__ float vos[T_][O_];   // 10 KB
    const int b = blockIdx.x;
    const int tid = threadIdx.x;
    if (tid < O_) {
        float vo = 0.f;
        vos[0][tid] = 0.f;          // vo[0] stays zero
        for (int sp = 0; sp < ST_; ++sp) {
            vo = KAPPA_F * vo + zo[((size_t)sp * B_ + b) * O_ + tid];
            vos[sp + 1][tid] = vo;
        }
    }
    __syncthreads();
    for (int t = tid; t < T_; t += 64) {
        float m = -1e30f;
        #pragma unroll
        for (int o = 0; o < O_; ++o) m = fmaxf(m, vos[t][o]);
        float e[O_];
        float ssum = 0.f;
        #pragma unroll
        for (int o = 0; o < O_; ++o) {
            const float ee = expf(vos[t][o] - m);
            e[o] = ee;
            ssum += ee;
        }
        const float inv = 1.f / ssum;
        #pragma unroll
        for (int o = 0; o < O_; ++o)
            out[((size_t)t * B_ + b) * O_ + o] = e[o] * inv;
    }
}

extern "C" void kernel_launch(void* const* d_in, const int* in_sizes, int n_in,
                              void* d_out, int out_size, void* d_ws, size_t ws_size,
                              hipStream_t stream) {
    const float* x     = (const float*)d_in[0];   // [128,256,512]
    const float* w_in  = (const float*)d_in[1];   // [1024,512]
    const float* w_rec = (const float*)d_in[2];   // [1024,1024]
    const float* w_out = (const float*)d_in[3];   // [20,1024]
    float* out = (float*)d_out;                   // [128,256,20]

    // ws layout: WrecT(4MB) | WinT(2MB) | v(1MB) | z0(32KB) | zhist(4.15MB)
    //            | zo(2.6MB) | qbuf(G MB, adaptive)
    float*    WrecT = (float*)d_ws;
    float*    WinT  = WrecT + (size_t)H_ * H_;
    float*    v     = WinT  + (size_t)D_ * H_;
    unsigned* z0    = (unsigned*)(v + (size_t)B_ * H_);
    unsigned* zhist = z0 + (size_t)B_ * WPB;
    float*    zo    = (float*)(zhist + (size_t)ST_ * B_ * WPB);
    float*    qbuf  = zo + (size_t)ST_ * B_ * O_;

    const size_t used = (size_t)((char*)qbuf - (char*)d_ws);
    const size_t qstep = (size_t)B_ * H_ * sizeof(float);   // 1 MB per step
    size_t avail = (ws_size > used) ? (ws_size - used) : 0;
    int G = (int)(avail / qstep);
    if (G < 1)  G = 1;
    if (G > ST_) G = ST_;

    transpose_k<<<dim3(32, 32), 256, 0, stream>>>(w_rec, WrecT, H_, H_, 1);
    transpose_k<<<dim3(16, 32), 256, 0, stream>>>(w_in,  WinT,  H_, D_, 0);
    srnn_init<<<(B_ * H_ + 255) / 256, 256, 0, stream>>>(v, z0);

    const unsigned* zprev = z0;
    for (int s0 = 0; s0 < ST_; s0 += G) {
        const int gc = (ST_ - s0 < G) ? (ST_ - s0) : G;
        srnn_qsum<<<gc * 16, 256, 0, stream>>>(x, WinT, qbuf, s0, gc);
        for (int sl = 0; sl < gc; ++sl) {
            const int s = s0 + sl;
            unsigned* zcur = zhist + (size_t)s * B_ * WPB;
            srnn_step<<<512, 512, 0, stream>>>(
                WrecT, qbuf + (size_t)sl * B_ * H_, zprev, zcur, v);
            zprev = zcur;
        }
    }

    srnn_zo<<<ST_ * 16, 256, 0, stream>>>(zhist, w_out, zo);
    srnn_scan<<<B_, 64, 0, stream>>>(zo, out);
}